// Round 2
// baseline (55.272 us; speedup 1.0000x reference)
//
#include <hip/hip_runtime.h>
#include <hip/hip_bf16.h>

typedef float  f32x4  __attribute__((ext_vector_type(4)));
typedef short  bf16x8 __attribute__((ext_vector_type(8)));
typedef short  s16x4  __attribute__((ext_vector_type(4)));

#define NB   64
#define NL1  512
#define NL2  32
#define ND   600
#define NDP  640      // LDS row stride in shorts: 80 chunks (mult of 8 -> XOR-swizzle closed)
#define NW1  608      // w1 padded to mult of 32
#define ROWS 64       // ctx rows per block (4 waves x 16)

static __device__ __forceinline__ short f2bf(float f) {
    __hip_bfloat16 h = __float2bfloat16(f);
    return __builtin_bit_cast(short, h);
}

// out[b,i,j] = ctx[b,i,:].w1 + asp[b,j,:].w2 + sum_d ctx[b,i,d]*w3[d]*asp[b,j,d]
__global__ __launch_bounds__(256, 2)
void align_kernel(const float* __restrict__ ctx,
                  const float* __restrict__ asp,
                  const float* __restrict__ wu,
                  float* __restrict__ out)
{
    // aspw3: [32][640] bf16 bits; 16B-chunk XOR swizzle (chunk ^= row&7) kills
    // the bank conflict of stride-1280B ds_read_b128 column reads (2-way = free).
    // 80 chunks/row => XOR with 0..7 stays in-bounds (round-1 bug: 76 chunks leaked).
    __shared__ short aspw3[NL2 * NDP];
    __shared__ float w1s[NW1];
    __shared__ float ctterm[ROWS];
    __shared__ float aspterm[NL2];

    const int tid     = threadIdx.x;
    const int lane    = tid & 63;
    const int wid     = tid >> 6;
    const int b       = blockIdx.y;
    const int rowbase = blockIdx.x * ROWS;

    // ---- stage w1 (zero-padded to 608) ----
    for (int i = tid; i < NW1; i += 256)
        w1s[i] = (i < ND) ? wu[i] : 0.f;

    // ---- stage asp*w3 (bf16, swizzled) + asp_term ----
    {
        const int j  = tid >> 3;     // asp row 0..31
        const int e  = tid & 7;
        const int jx = j & 7;

        // zero-pad chunk 75 (k = 600..607) of every row
        aspw3[j * NDP + ((75 ^ jx) << 3) + e] = 0;

        const int sub = tid & 7;     // 8 threads per row, float4 each
        const float* arow = asp + ((size_t)b * NL2 + j) * ND;
        float at = 0.f;
        #pragma unroll
        for (int m = 0; m < 19; ++m) {
            const int k = m * 32 + sub * 4;
            if (k < ND) {
                const float4 v  = *(const float4*)(arow + k);
                const float4 w2 = *(const float4*)(wu + ND + k);
                const float4 w3 = *(const float4*)(wu + 2 * ND + k);
                at += v.x * w2.x + v.y * w2.y + v.z * w2.z + v.w * w2.w;
                s16x4 h;
                h.x = f2bf(v.x * w3.x);
                h.y = f2bf(v.y * w3.y);
                h.z = f2bf(v.z * w3.z);
                h.w = f2bf(v.w * w3.w);
                const int c = (k >> 3) ^ jx;          // swizzled 16B chunk, in [0,80)
                *(s16x4*)&aspw3[j * NDP + (c << 3) + (k & 7)] = h;
            }
        }
        at += __shfl_xor(at, 1);
        at += __shfl_xor(at, 2);
        at += __shfl_xor(at, 4);
        if (sub == 0) aspterm[j] = at;
    }
    __syncthreads();

    // ---- main loop: D[i][j] = sum_k ctx[i][k] * (w3[k]*asp[j][k]) ----
    const int r16 = lane & 15;            // A row / B col / D col index
    const int g   = lane >> 4;            // k-group
    const int jx  = lane & 7;             // == (row being read) & 7 for both b0,b1
    const float* actx = ctx + ((size_t)b * NL1 + rowbase + wid * 16 + r16) * ND + 8 * g;

    f32x4 acc0 = {0.f, 0.f, 0.f, 0.f};
    f32x4 acc1 = {0.f, 0.f, 0.f, 0.f};
    float ct = 0.f;

    for (int s = 0; s < 18; ++s) {        // full K-steps, k < 576
        const int k0 = s * 32;
        const float4 v0 = *(const float4*)(actx + k0);
        const float4 v1 = *(const float4*)(actx + k0 + 4);
        const float4 w1a = *(const float4*)&w1s[k0 + 8 * g];
        const float4 w1b = *(const float4*)&w1s[k0 + 8 * g + 4];
        ct += v0.x * w1a.x + v0.y * w1a.y + v0.z * w1a.z + v0.w * w1a.w
            + v1.x * w1b.x + v1.y * w1b.y + v1.z * w1b.z + v1.w * w1b.w;
        bf16x8 af;
        af[0] = f2bf(v0.x); af[1] = f2bf(v0.y); af[2] = f2bf(v0.z); af[3] = f2bf(v0.w);
        af[4] = f2bf(v1.x); af[5] = f2bf(v1.y); af[6] = f2bf(v1.z); af[7] = f2bf(v1.w);
        const int c = ((s * 4 + g) ^ jx) << 3;
        const bf16x8 b0 = *(const bf16x8*)&aspw3[r16 * NDP + c];
        const bf16x8 b1 = *(const bf16x8*)&aspw3[(16 + r16) * NDP + c];
        acc0 = __builtin_amdgcn_mfma_f32_16x16x32_bf16(af, b0, acc0, 0, 0, 0);
        acc1 = __builtin_amdgcn_mfma_f32_16x16x32_bf16(af, b1, acc1, 0, 0, 0);
    }
    {   // tail K-step: k0 = 576, valid k < 600 -> lane groups g<3 only
        const int k0 = 576;
        float4 v0 = make_float4(0.f, 0.f, 0.f, 0.f);
        float4 v1 = make_float4(0.f, 0.f, 0.f, 0.f);
        if (g < 3) {
            v0 = *(const float4*)(actx + k0);
            v1 = *(const float4*)(actx + k0 + 4);
        }
        const float4 w1a = *(const float4*)&w1s[k0 + 8 * g];
        const float4 w1b = *(const float4*)&w1s[k0 + 8 * g + 4];
        ct += v0.x * w1a.x + v0.y * w1a.y + v0.z * w1a.z + v0.w * w1a.w
            + v1.x * w1b.x + v1.y * w1b.y + v1.z * w1b.z + v1.w * w1b.w;
        bf16x8 af;
        af[0] = f2bf(v0.x); af[1] = f2bf(v0.y); af[2] = f2bf(v0.z); af[3] = f2bf(v0.w);
        af[4] = f2bf(v1.x); af[5] = f2bf(v1.y); af[6] = f2bf(v1.z); af[7] = f2bf(v1.w);
        const int c = ((18 * 4 + g) ^ jx) << 3;
        const bf16x8 b0 = *(const bf16x8*)&aspw3[r16 * NDP + c];
        const bf16x8 b1 = *(const bf16x8*)&aspw3[(16 + r16) * NDP + c];
        acc0 = __builtin_amdgcn_mfma_f32_16x16x32_bf16(af, b0, acc0, 0, 0, 0);
        acc1 = __builtin_amdgcn_mfma_f32_16x16x32_bf16(af, b1, acc1, 0, 0, 0);
    }

    // ---- ctx_term: reduce over k-groups (lanes r16, r16+16, +32, +48) ----
    ct += __shfl_xor(ct, 16);
    ct += __shfl_xor(ct, 32);
    if (lane < 16) ctterm[wid * 16 + lane] = ct;
    __syncthreads();

    // ---- epilogue: D row = g*4 + reg, D col = r16 (verified C/D map, m89) ----
    const float atj0 = aspterm[r16];
    const float atj1 = aspterm[16 + r16];
    float* orow = out + ((size_t)b * NL1 + rowbase + wid * 16 + g * 4) * NL2;
    #pragma unroll
    for (int r = 0; r < 4; ++r) {
        const float cterm = ctterm[wid * 16 + g * 4 + r];
        orow[r * NL2 + r16]      = acc0[r] + cterm + atj0;
        orow[r * NL2 + 16 + r16] = acc1[r] + cterm + atj1;
    }
}

extern "C" void kernel_launch(void* const* d_in, const int* in_sizes, int n_in,
                              void* d_out, int out_size, void* d_ws, size_t ws_size,
                              hipStream_t stream) {
    (void)in_sizes; (void)n_in; (void)d_ws; (void)ws_size; (void)out_size;
    // d_in: [0]=batch_size(int scalar), [1]=ctx f32, [2]=asp f32, [3]=w_u f32
    const float* ctx = (const float*)d_in[1];
    const float* asp = (const float*)d_in[2];
    const float* wu  = (const float*)d_in[3];
    float* out = (float*)d_out;
    dim3 grid(NL1 / ROWS, NB);
    align_kernel<<<grid, 256, 0, stream>>>(ctx, asp, wu, out);
}

// Round 3
// 21.922 us; speedup vs baseline: 2.5213x; 2.5213x over previous
//
#include <hip/hip_runtime.h>
#include <hip/hip_bf16.h>

typedef float  f32x4  __attribute__((ext_vector_type(4)));
typedef short  bf16x8 __attribute__((ext_vector_type(8)));
typedef short  s16x4  __attribute__((ext_vector_type(4)));

#define NB   64
#define NL1  512
#define NL2  32
#define ND   600
#define NDP  640      // LDS row stride in shorts: 80 chunks (mult of 8 -> XOR-swizzle closed)
#define NW1  608      // w1 padded to mult of 32
#define ROWS 64       // ctx rows per block (4 waves x 16)

static __device__ __forceinline__ short f2bf(float f) {
    __hip_bfloat16 h = __float2bfloat16(f);
    return __builtin_bit_cast(short, h);
}

// out[b,i,j] = ctx[b,i,:].w1 + asp[b,j,:].w2 + sum_d ctx[b,i,d]*w3[d]*asp[b,j,d]
__global__ __launch_bounds__(256, 2)
void align_kernel(const float* __restrict__ ctx,
                  const float* __restrict__ asp,
                  const float* __restrict__ wu,
                  float* __restrict__ out)
{
    __shared__ short aspw3[NL2 * NDP];   // [32][640] bf16 bits, 16B-chunk XOR swizzle
    __shared__ float w1s[NW1];
    __shared__ float ctterm[ROWS];
    __shared__ float aspterm[NL2];

    const int tid     = threadIdx.x;
    const int lane    = tid & 63;
    const int wid     = tid >> 6;
    // grid = (batch, tile): same-batch tiles get block ids b + 64*t -> same XCD
    // (id % 8 == b % 8) -> asp panel is L2-local, fetched ~once per batch.
    const int b       = blockIdx.x;
    const int rowbase = blockIdx.y * ROWS;

    const int r16 = lane & 15;            // A row / B col / D col index
    const int g   = lane >> 4;            // k-group
    const int jx  = lane & 7;
    const float* actx = ctx + ((size_t)b * NL1 + rowbase + wid * 16 + r16) * ND + 8 * g;

    // prologue ctx load (s=0) issued BEFORE staging: latency hides under staging+barrier
    float4 v0 = *(const float4*)(actx);
    float4 v1 = *(const float4*)(actx + 4);

    // ---- stage w1 (zero-padded to 608) ----
    for (int i = tid; i < NW1; i += 256)
        w1s[i] = (i < ND) ? wu[i] : 0.f;

    // ---- stage asp*w3 (bf16, swizzled) + asp_term ----
    {
        const int j   = tid >> 3;    // asp row 0..31
        const int e   = tid & 7;
        const int jxs = j & 7;

        // zero-pad chunk 75 (k = 600..607) of every row
        aspw3[j * NDP + ((75 ^ jxs) << 3) + e] = 0;

        const int sub = tid & 7;     // 8 threads per row, float4 each
        const float* arow = asp + ((size_t)b * NL2 + j) * ND;
        float at = 0.f;
        #pragma unroll
        for (int m = 0; m < 19; ++m) {
            const int k = m * 32 + sub * 4;
            if (k < ND) {
                const float4 v  = *(const float4*)(arow + k);
                const float4 w2 = *(const float4*)(wu + ND + k);
                const float4 w3 = *(const float4*)(wu + 2 * ND + k);
                at += v.x * w2.x + v.y * w2.y + v.z * w2.z + v.w * w2.w;
                s16x4 h;
                h.x = f2bf(v.x * w3.x);
                h.y = f2bf(v.y * w3.y);
                h.z = f2bf(v.z * w3.z);
                h.w = f2bf(v.w * w3.w);
                const int c = (k >> 3) ^ jxs;         // swizzled 16B chunk, in [0,80)
                *(s16x4*)&aspw3[j * NDP + (c << 3) + (k & 7)] = h;
            }
        }
        at += __shfl_xor(at, 1);
        at += __shfl_xor(at, 2);
        at += __shfl_xor(at, 4);
        if (sub == 0) aspterm[j] = at;
    }
    __syncthreads();

    // ---- main loop: rolled, depth-1 register prefetch (no compiler mega-unroll,
    //      which spilled all 36 hoisted ctx loads to scratch: 19x WRITE_SIZE) ----
    f32x4 acc0 = {0.f, 0.f, 0.f, 0.f};
    f32x4 acc1 = {0.f, 0.f, 0.f, 0.f};
    float ct = 0.f;

    #pragma unroll 1
    for (int s = 0; s < 19; ++s) {
        // prefetch step s+1 (uniform branch; tail step masks lane-groups g>=3)
        float4 n0 = make_float4(0.f, 0.f, 0.f, 0.f);
        float4 n1 = make_float4(0.f, 0.f, 0.f, 0.f);
        if (s < 17) {
            n0 = *(const float4*)(actx + (s + 1) * 32);
            n1 = *(const float4*)(actx + (s + 1) * 32 + 4);
        } else if (s == 17) {
            if (g < 3) {
                n0 = *(const float4*)(actx + 18 * 32);
                n1 = *(const float4*)(actx + 18 * 32 + 4);
            }
        }

        const int k0 = s * 32;
        const float4 w1a = *(const float4*)&w1s[k0 + 8 * g];
        const float4 w1b = *(const float4*)&w1s[k0 + 8 * g + 4];
        ct += v0.x * w1a.x + v0.y * w1a.y + v0.z * w1a.z + v0.w * w1a.w
            + v1.x * w1b.x + v1.y * w1b.y + v1.z * w1b.z + v1.w * w1b.w;
        bf16x8 af;
        af[0] = f2bf(v0.x); af[1] = f2bf(v0.y); af[2] = f2bf(v0.z); af[3] = f2bf(v0.w);
        af[4] = f2bf(v1.x); af[5] = f2bf(v1.y); af[6] = f2bf(v1.z); af[7] = f2bf(v1.w);
        const int c = ((s * 4 + g) ^ jx) << 3;
        const bf16x8 b0 = *(const bf16x8*)&aspw3[r16 * NDP + c];
        const bf16x8 b1 = *(const bf16x8*)&aspw3[(16 + r16) * NDP + c];
        acc0 = __builtin_amdgcn_mfma_f32_16x16x32_bf16(af, b0, acc0, 0, 0, 0);
        acc1 = __builtin_amdgcn_mfma_f32_16x16x32_bf16(af, b1, acc1, 0, 0, 0);

        v0 = n0; v1 = n1;
    }

    // ---- ctx_term: reduce over k-groups (lanes r16, r16+16, +32, +48) ----
    ct += __shfl_xor(ct, 16);
    ct += __shfl_xor(ct, 32);
    if (lane < 16) ctterm[wid * 16 + lane] = ct;
    __syncthreads();

    // ---- epilogue: D row = g*4 + reg, D col = r16 (verified C/D map, m89) ----
    const float atj0 = aspterm[r16];
    const float atj1 = aspterm[16 + r16];
    float* orow = out + ((size_t)b * NL1 + rowbase + wid * 16 + g * 4) * NL2;
    #pragma unroll
    for (int r = 0; r < 4; ++r) {
        const float cterm = ctterm[wid * 16 + g * 4 + r];
        orow[r * NL2 + r16]      = acc0[r] + cterm + atj0;
        orow[r * NL2 + 16 + r16] = acc1[r] + cterm + atj1;
    }
}

extern "C" void kernel_launch(void* const* d_in, const int* in_sizes, int n_in,
                              void* d_out, int out_size, void* d_ws, size_t ws_size,
                              hipStream_t stream) {
    (void)in_sizes; (void)n_in; (void)d_ws; (void)ws_size; (void)out_size;
    // d_in: [0]=batch_size(int scalar), [1]=ctx f32, [2]=asp f32, [3]=w_u f32
    const float* ctx = (const float*)d_in[1];
    const float* asp = (const float*)d_in[2];
    const float* wu  = (const float*)d_in[3];
    float* out = (float*)d_out;
    dim3 grid(NB, NL1 / ROWS);
    align_kernel<<<grid, 256, 0, stream>>>(ctx, asp, wu, out);
}

// Round 4
// 21.844 us; speedup vs baseline: 2.5303x; 1.0036x over previous
//
#include <hip/hip_runtime.h>
#include <hip/hip_bf16.h>

typedef float  f32x4  __attribute__((ext_vector_type(4)));
typedef short  bf16x8 __attribute__((ext_vector_type(8)));
typedef short  s16x4  __attribute__((ext_vector_type(4)));

#define NB   64
#define NL1  512
#define NL2  32
#define ND   600
#define NDP  640      // LDS row stride in shorts: 80 chunks (mult of 8 -> XOR-swizzle closed)
#define NW1  608      // w1 padded to mult of 32
#define ROWS 64       // ctx rows per block (4 waves x 16)

static __device__ __forceinline__ short f2bf(float f) {
    __hip_bfloat16 h = __float2bfloat16(f);
    return __builtin_bit_cast(short, h);
}

// out[b,i,j] = ctx[b,i,:].w1 + asp[b,j,:].w2 + sum_d ctx[b,i,d]*w3[d]*asp[b,j,d]
__global__ __launch_bounds__(256, 2)
void align_kernel(const float* __restrict__ ctx,
                  const float* __restrict__ asp,
                  const float* __restrict__ wu,
                  float* __restrict__ out)
{
    __shared__ short aspw3[NL2 * NDP];   // [32][640] bf16 bits, 16B-chunk XOR swizzle
    __shared__ short w1bf[NW1];          // w1 as bf16 (B-fragment broadcast for acc2)
    __shared__ float aspterm[NL2];

    const int tid     = threadIdx.x;
    const int lane    = tid & 63;
    const int wid     = tid >> 6;
    // grid = (batch, tile): same-batch tiles get block ids b + 64*t -> same XCD
    const int b       = blockIdx.x;
    const int rowbase = blockIdx.y * ROWS;

    const int r16 = lane & 15;            // A row / B col / D col index
    const int g   = lane >> 4;            // k-group
    const int jx  = lane & 7;
    const float* actx = ctx + ((size_t)b * NL1 + rowbase + wid * 16 + r16) * ND + 8 * g;

    // prologue ctx loads (s=0,1) issued BEFORE staging: latency hides under staging
    float4 v0 = *(const float4*)(actx);
    float4 v1 = *(const float4*)(actx + 4);
    float4 n0 = *(const float4*)(actx + 32);
    float4 n1 = *(const float4*)(actx + 36);

    // ---- stage w1 as bf16 (zero-padded to 608) ----
    for (int i = tid; i < NW1; i += 256)
        w1bf[i] = (i < ND) ? f2bf(wu[i]) : (short)0;

    // ---- stage asp*w3 (bf16, swizzled) + asp_term ----
    {
        const int j   = tid >> 3;    // asp row 0..31
        const int e   = tid & 7;
        const int jxs = j & 7;

        // zero-pad chunk 75 (k = 600..607) of every row
        aspw3[j * NDP + ((75 ^ jxs) << 3) + e] = 0;

        const int sub = tid & 7;     // 8 threads per row, float4 each
        const float* arow = asp + ((size_t)b * NL2 + j) * ND;
        float at = 0.f;
        #pragma unroll
        for (int m = 0; m < 19; ++m) {
            const int k = m * 32 + sub * 4;
            if (k < ND) {
                const float4 v  = *(const float4*)(arow + k);
                const float4 w2 = *(const float4*)(wu + ND + k);
                const float4 w3 = *(const float4*)(wu + 2 * ND + k);
                at += v.x * w2.x + v.y * w2.y + v.z * w2.z + v.w * w2.w;
                s16x4 h;
                h.x = f2bf(v.x * w3.x);
                h.y = f2bf(v.y * w3.y);
                h.z = f2bf(v.z * w3.z);
                h.w = f2bf(v.w * w3.w);
                const int c = (k >> 3) ^ jxs;         // swizzled 16B chunk, in [0,80)
                *(s16x4*)&aspw3[j * NDP + (c << 3) + (k & 7)] = h;
            }
        }
        at += __shfl_xor(at, 1);
        at += __shfl_xor(at, 2);
        at += __shfl_xor(at, 4);
        if (sub == 0) aspterm[j] = at;
    }
    __syncthreads();

    // ---- main loop: rolled, depth-2 register prefetch ----
    // acc2: B = broadcast w1 -> every D col = ctx[row].w1; lane (g,r16) reg r
    // holds ctterm[g*4+r] exactly where the epilogue needs it (no shuffle/LDS).
    f32x4 acc0 = {0.f, 0.f, 0.f, 0.f};
    f32x4 acc1 = {0.f, 0.f, 0.f, 0.f};
    f32x4 acc2 = {0.f, 0.f, 0.f, 0.f};

    #pragma unroll 1
    for (int s = 0; s < 19; ++s) {
        // prefetch step s+2 (uniform branch; tail step masks lane-group g=3)
        float4 p0 = make_float4(0.f, 0.f, 0.f, 0.f);
        float4 p1 = make_float4(0.f, 0.f, 0.f, 0.f);
        if (s < 16) {
            p0 = *(const float4*)(actx + (s + 2) * 32);
            p1 = *(const float4*)(actx + (s + 2) * 32 + 4);
        } else if (s == 16) {
            if (g < 3) {
                p0 = *(const float4*)(actx + 18 * 32);
                p1 = *(const float4*)(actx + 18 * 32 + 4);
            }
        }

        const int k0 = s * 32;
        bf16x8 af;
        af[0] = f2bf(v0.x); af[1] = f2bf(v0.y); af[2] = f2bf(v0.z); af[3] = f2bf(v0.w);
        af[4] = f2bf(v1.x); af[5] = f2bf(v1.y); af[6] = f2bf(v1.z); af[7] = f2bf(v1.w);
        const int c = ((s * 4 + g) ^ jx) << 3;
        const bf16x8 b0 = *(const bf16x8*)&aspw3[r16 * NDP + c];
        const bf16x8 b1 = *(const bf16x8*)&aspw3[(16 + r16) * NDP + c];
        const bf16x8 wf = *(const bf16x8*)&w1bf[k0 + 8 * g];   // broadcast read
        acc0 = __builtin_amdgcn_mfma_f32_16x16x32_bf16(af, b0, acc0, 0, 0, 0);
        acc1 = __builtin_amdgcn_mfma_f32_16x16x32_bf16(af, b1, acc1, 0, 0, 0);
        acc2 = __builtin_amdgcn_mfma_f32_16x16x32_bf16(af, wf, acc2, 0, 0, 0);

        v0 = n0; v1 = n1;
        n0 = p0; n1 = p1;
    }

    // ---- epilogue: D row = g*4 + reg, D col = r16 (verified C/D map, m89) ----
    const float atj0 = aspterm[r16];
    const float atj1 = aspterm[16 + r16];
    float* orow = out + ((size_t)b * NL1 + rowbase + wid * 16 + g * 4) * NL2;
    #pragma unroll
    for (int r = 0; r < 4; ++r) {
        const float cterm = acc2[r];
        orow[r * NL2 + r16]      = acc0[r] + cterm + atj0;
        orow[r * NL2 + 16 + r16] = acc1[r] + cterm + atj1;
    }
}

extern "C" void kernel_launch(void* const* d_in, const int* in_sizes, int n_in,
                              void* d_out, int out_size, void* d_ws, size_t ws_size,
                              hipStream_t stream) {
    (void)in_sizes; (void)n_in; (void)d_ws; (void)ws_size; (void)out_size;
    // d_in: [0]=batch_size(int scalar), [1]=ctx f32, [2]=asp f32, [3]=w_u f32
    const float* ctx = (const float*)d_in[1];
    const float* asp = (const float*)d_in[2];
    const float* wu  = (const float*)d_in[3];
    float* out = (float*)d_out;
    dim3 grid(NB, NL1 / ROWS);
    align_kernel<<<grid, 256, 0, stream>>>(ctx, asp, wu, out);
}

// Round 5
// 21.652 us; speedup vs baseline: 2.5528x; 1.0089x over previous
//
#include <hip/hip_runtime.h>
#include <hip/hip_bf16.h>

typedef float  f32x4  __attribute__((ext_vector_type(4)));
typedef short  bf16x8 __attribute__((ext_vector_type(8)));
typedef short  s16x4  __attribute__((ext_vector_type(4)));

#define NB   64
#define NL1  512
#define NL2  32
#define ND   600
#define NDP  640      // LDS row stride in shorts: 80 chunks (mult of 8 -> XOR-swizzle closed)
#define NW1  608      // w1 padded to mult of 32
#define ROWS 64       // ctx rows per block (4 waves x 16)

static __device__ __forceinline__ short f2bf(float f) {
    __hip_bfloat16 h = __float2bfloat16(f);
    return __builtin_bit_cast(short, h);
}

// out[b,i,j] = ctx[b,i,:].w1 + asp[b,j,:].w2 + sum_d ctx[b,i,d]*w3[d]*asp[b,j,d]
__global__ __launch_bounds__(256, 2)
void align_kernel(const float* __restrict__ ctx,
                  const float* __restrict__ asp,
                  const float* __restrict__ wu,
                  float* __restrict__ out)
{
    __shared__ short aspw3[NL2 * NDP];   // [32][640] bf16 bits, 16B-chunk XOR swizzle
    __shared__ short w1bf[NW1];          // w1 as bf16 (broadcast B-fragment for acc2)
    __shared__ float aspterm[NL2];

    const int tid     = threadIdx.x;
    const int lane    = tid & 63;
    const int wid     = tid >> 6;
    // grid = (batch, tile): same-batch tiles -> same XCD -> asp panel L2-local
    const int b       = blockIdx.x;
    const int rowbase = blockIdx.y * ROWS;

    const int r16 = lane & 15;            // A row / B col / D col index
    const int g   = lane >> 4;            // k-group
    const int jx  = lane & 7;
    const float* actx = ctx + ((size_t)b * NL1 + rowbase + wid * 16 + r16) * ND + 8 * g;

    // 4-deep pipeline buffers; steps 0..3 issued BEFORE staging (overlap staging)
    float4 a0 = *(const float4*)(actx);       float4 b0 = *(const float4*)(actx + 4);
    float4 a1 = *(const float4*)(actx + 32);  float4 b1 = *(const float4*)(actx + 36);
    float4 a2 = *(const float4*)(actx + 64);  float4 b2 = *(const float4*)(actx + 68);
    float4 a3 = *(const float4*)(actx + 96);  float4 b3 = *(const float4*)(actx + 100);

    // ---- stage w1 as bf16 (zero-padded to 608) ----
    for (int i = tid; i < NW1; i += 256)
        w1bf[i] = (i < ND) ? f2bf(wu[i]) : (short)0;

    // ---- stage asp*w3 (bf16, swizzled) + asp_term ----
    {
        const int j   = tid >> 3;    // asp row 0..31
        const int e   = tid & 7;
        const int jxs = j & 7;

        // zero-pad chunk 75 (k = 600..607) of every row
        aspw3[j * NDP + ((75 ^ jxs) << 3) + e] = 0;

        const int sub = tid & 7;     // 8 threads per row, float4 each
        const float* arow = asp + ((size_t)b * NL2 + j) * ND;
        float at = 0.f;
        #pragma unroll
        for (int m = 0; m < 19; ++m) {
            const int k = m * 32 + sub * 4;
            if (k < ND) {
                const float4 v  = *(const float4*)(arow + k);
                const float4 w2 = *(const float4*)(wu + ND + k);
                const float4 w3 = *(const float4*)(wu + 2 * ND + k);
                at += v.x * w2.x + v.y * w2.y + v.z * w2.z + v.w * w2.w;
                s16x4 h;
                h.x = f2bf(v.x * w3.x);
                h.y = f2bf(v.y * w3.y);
                h.z = f2bf(v.z * w3.z);
                h.w = f2bf(v.w * w3.w);
                const int c = (k >> 3) ^ jxs;         // swizzled 16B chunk, in [0,80)
                *(s16x4*)&aspw3[j * NDP + (c << 3) + (k & 7)] = h;
            }
        }
        at += __shfl_xor(at, 1);
        at += __shfl_xor(at, 2);
        at += __shfl_xor(at, 4);
        if (sub == 0) aspterm[j] = at;
    }
    __syncthreads();

    // ---- main loop: 4-deep / 4-wide manual software pipeline.
    // No register rotation across iterations (each slot renamed per copy),
    // so the steady-state wait is vmcnt(~8), keeping ~8 16B loads/lane in
    // flight (64 KB/CU) instead of the rotation-forced ~2.
    f32x4 acc0 = {0.f, 0.f, 0.f, 0.f};
    f32x4 acc1 = {0.f, 0.f, 0.f, 0.f};
    f32x4 acc2 = {0.f, 0.f, 0.f, 0.f};

#define PIPE_STEP(u, aU, bU)                                                   \
    {                                                                          \
        const int s = s0 + (u);                                                \
        if (s < 19) {                                                          \
            const int t = s + 4;                                               \
            float4 p0, p1;                                                     \
            if ((t <= 17) || (t == 18 && g < 3)) {                             \
                p0 = *(const float4*)(actx + t * 32);                          \
                p1 = *(const float4*)(actx + t * 32 + 4);                      \
            } else {                                                           \
                p0 = make_float4(0.f, 0.f, 0.f, 0.f);                          \
                p1 = make_float4(0.f, 0.f, 0.f, 0.f);                          \
            }                                                                  \
            bf16x8 af;                                                         \
            af[0] = f2bf(aU.x); af[1] = f2bf(aU.y);                            \
            af[2] = f2bf(aU.z); af[3] = f2bf(aU.w);                            \
            af[4] = f2bf(bU.x); af[5] = f2bf(bU.y);                            \
            af[6] = f2bf(bU.z); af[7] = f2bf(bU.w);                            \
            const int c = ((s * 4 + g) ^ jx) << 3;                             \
            const bf16x8 f0 = *(const bf16x8*)&aspw3[r16 * NDP + c];           \
            const bf16x8 f1 = *(const bf16x8*)&aspw3[(16 + r16) * NDP + c];    \
            const bf16x8 wf = *(const bf16x8*)&w1bf[s * 32 + 8 * g];           \
            acc0 = __builtin_amdgcn_mfma_f32_16x16x32_bf16(af, f0, acc0, 0, 0, 0); \
            acc1 = __builtin_amdgcn_mfma_f32_16x16x32_bf16(af, f1, acc1, 0, 0, 0); \
            acc2 = __builtin_amdgcn_mfma_f32_16x16x32_bf16(af, wf, acc2, 0, 0, 0); \
            aU = p0; bU = p1;                                                  \
        }                                                                      \
    }

    #pragma unroll 1
    for (int s0 = 0; s0 < 19; s0 += 4) {
        PIPE_STEP(0, a0, b0)
        PIPE_STEP(1, a1, b1)
        PIPE_STEP(2, a2, b2)
        PIPE_STEP(3, a3, b3)
    }
#undef PIPE_STEP

    // ---- epilogue: D row = g*4 + reg, D col = r16 (verified C/D map, m89) ----
    const float atj0 = aspterm[r16];
    const float atj1 = aspterm[16 + r16];
    float* orow = out + ((size_t)b * NL1 + rowbase + wid * 16 + g * 4) * NL2;
    #pragma unroll
    for (int r = 0; r < 4; ++r) {
        const float cterm = acc2[r];
        orow[r * NL2 + r16]      = acc0[r] + cterm + atj0;
        orow[r * NL2 + 16 + r16] = acc1[r] + cterm + atj1;
    }
}

extern "C" void kernel_launch(void* const* d_in, const int* in_sizes, int n_in,
                              void* d_out, int out_size, void* d_ws, size_t ws_size,
                              hipStream_t stream) {
    (void)in_sizes; (void)n_in; (void)d_ws; (void)ws_size; (void)out_size;
    // d_in: [0]=batch_size(int scalar), [1]=ctx f32, [2]=asp f32, [3]=w_u f32
    const float* ctx = (const float*)d_in[1];
    const float* asp = (const float*)d_in[2];
    const float* wu  = (const float*)d_in[3];
    float* out = (float*)d_out;
    dim3 grid(NB, NL1 / ROWS);
    align_kernel<<<grid, 256, 0, stream>>>(ctx, asp, wu, out);
}